// Round 7
// baseline (150.932 us; speedup 1.0000x reference)
//
#include <hip/hip_runtime.h>

// Signature-kernel MMD via Goursat PDE — round 7.
// R6 postmortem: pk_fma asm was UNTIED -> regalloc inserted ~16 v_mov/row to
// carry accumulators; instrs/row rose 71->80. R7 keeps the R2/R6 skeleton
// (diff precompute, 2112x4-wave grid, 1 pair/wave, SGPR x-rows via s_load,
// DPP scan) and fixes codegen: (1) tied "+v" pk_fma accumulators (zero movs;
// chain heads read a loop-invariant seed reg), (2) lane-63 cndmask dropped —
// bogus c1 self-cancels via g_lo = (S+1)-c1 and g_hi(63) is never consumed,
// (3) 2-op state epilogue. ~33 VALU/row (vs 71).

typedef float f2 __attribute__((ext_vector_type(2)));

#define XY_BLOCKS 1024
#define TRI_BLOCKS 544
#define NBLOCKS (XY_BLOCKS + 2 * TRI_BLOCKS)   // 2112 blocks x 4 waves
#define DINC_PER 130048                         // 64*127*16 floats

template <int C, int RM, int BM, bool BC>
__device__ __forceinline__ float dpp0(float x) {
    return __builtin_bit_cast(float, __builtin_amdgcn_update_dpp(
        0, __builtin_bit_cast(int, x), C, RM, BM, BC));
}

// 64-lane inclusive prefix sum, pure VALU (6 dependent v_add_f32_dpp).
__device__ __forceinline__ float wave_scan_incl(float v) {
    v += dpp0<0x111, 0xf, 0xf, true>(v);   // row_shr:1
    v += dpp0<0x112, 0xf, 0xf, true>(v);   // row_shr:2
    v += dpp0<0x114, 0xf, 0xf, true>(v);   // row_shr:4
    v += dpp0<0x118, 0xf, 0xf, true>(v);   // row_shr:8
    v += dpp0<0x142, 0xa, 0xf, false>(v);  // row_bcast:15 -> rows 1,3
    v += dpp0<0x143, 0xc, 0xf, false>(v);  // row_bcast:31 -> rows 2,3
    return v;
}

// lane l gets lane l-1's x; lane 0 gets `oldv`.
__device__ __forceinline__ float wave_shr1(float x, float oldv) {
    return __builtin_bit_cast(float, __builtin_amdgcn_update_dpp(
        __builtin_bit_cast(int, oldv), __builtin_bit_cast(int, x),
        0x138, 0xf, 0xf, false));          // wave_shr:1
}

// tied packed FMA: c += xs * yv   (xs from SGPR pair, zero movs)
__device__ __forceinline__ void pk_fma_acc(f2& c, f2 xs, f2 yv) {
    asm("v_pk_fma_f32 %0, %1, %2, %0"
        : "+v"(c)
        : "s"(__builtin_bit_cast(long, xs)), "v"(yv));
}
// chain head: d = xs * yv + seed  (seed is a loop-invariant register)
__device__ __forceinline__ f2 pk_fma_init(f2 xs, f2 yv, f2 seed) {
    f2 d;
    asm("v_pk_fma_f32 %0, %1, %2, %3"
        : "=v"(d)
        : "s"(__builtin_bit_cast(long, xs)), "v"(yv), "v"(seed));
    return d;
}

// x row r via wave-uniform address -> s_load into SGPR pairs
__device__ __forceinline__ void load_xrow(f2* x, const float4* Ar, int r) {
#pragma unroll
    for (int q = 0; q < 4; ++q) {
        float4 v = Ar[4 * r + q];
        x[2*q]   = f2{v.x, v.y};
        x[2*q+1] = f2{v.z, v.w};
    }
}

// both per-lane dots for one row: i0 = inc(r,2l)-1, i1 = inc(r,2l+1)-1
// seed register holds {-0.25,-0.25}: 4 partials per dot sum to (dot - 1).
__device__ __forceinline__ void row_dots(
    const f2* x, const f2* ya, const f2* yb, f2 seed, float& i0, float& i1)
{
    f2 a0 = pk_fma_init(x[0], ya[0], seed);
    f2 a1 = pk_fma_init(x[1], ya[1], seed);
    f2 b0 = pk_fma_init(x[0], yb[0], seed);
    f2 b1 = pk_fma_init(x[1], yb[1], seed);
#pragma unroll
    for (int d = 2; d < 8; d += 2) {
        pk_fma_acc(a0, x[d],   ya[d]);
        pk_fma_acc(a1, x[d+1], ya[d+1]);
        pk_fma_acc(b0, x[d],   yb[d]);
        pk_fma_acc(b1, x[d+1], yb[d+1]);
    }
    const f2 sA = a0 + a1, sB = b0 + b1;
    i0 = sA.x + sA.y;
    i1 = sB.x + sB.y;
}

// serial part of one PDE row; lane-63's c1 is bogus by construction but
// self-cancels: g_lo = (S+1) - c1, and g_hi(63) is never consumed.
__device__ __forceinline__ void recur(
    float i0, float i1, float& g_lo, float& g_hi)
{
    const float gl = wave_shr1(g_hi, 1.0f);        // G[r][2l], lane0 -> 1
    const float c0 = fmaf(gl, i0, g_lo);
    const float c1 = fmaf(g_lo, i1, g_hi);
    const float S = wave_scan_incl(c0 + c1);
    g_hi = S + 1.0f;
    g_lo = g_hi - c1;
}

// ---- kernel 1: path increments X,Y -> ws ----
__global__ __launch_bounds__(256) void sig_diff(
    const float* __restrict__ X, const float* __restrict__ Y,
    float* __restrict__ dInc)
{
    int i = blockIdx.x * 256 + threadIdx.x;   // float4 id, 65024 total
    if (i >= 65024) return;
    int which = (i >= 32512) ? 1 : 0;
    int j = i - which * 32512;
    int a = j / 508;                          // 127*4 float4 per path
    int rq = j - a * 508;
    const float* S = which ? Y : X;
    const float4* p = (const float4*)(S + a * 2048) + rq;
    float4 v0 = p[0], v1 = p[4];
    float4 d;
    d.x = v1.x - v0.x; d.y = v1.y - v0.y;
    d.z = v1.z - v0.z; d.w = v1.w - v0.w;
    ((float4*)dInc)[i] = d;
}

// ---- kernel 2: PDE, 1 pair/wave, fused block reduction ----
__global__ __launch_bounds__(256) void sig_pde7(
    const float* __restrict__ dInc, float* __restrict__ outp)
{
    __shared__ float red[4];
    const int wv = threadIdx.x >> 6, lane = threadIdx.x & 63;
    const int B = blockIdx.x;

    int g, a, b;
    if (B < XY_BLOCKS) {                       // XY gram: dense 64x64
        g = 2; a = B >> 4; b = ((B & 15) << 2) + wv;
    } else {                                   // XX / YY: upper triangle
        int t = B - XY_BLOCKS; g = 0;
        if (t >= TRI_BLOCKS) { t -= TRI_BLOCKS; g = 1; }
        int aa = 0;
        for (;;) { int nb = (67 - aa) >> 2; if (t < nb) break; t -= nb; ++aa; }
        a = aa; b = aa + (t << 2) + wv;
    }
    float weight = (g == 2) ? (-2.0f / 4096.0f)
                            : ((a == b ? 1.0f : 2.0f) / 4096.0f);
    if (g < 2 && b > 63) { b = 63; weight = 0.0f; }   // pad waves: masked

    const float* dA = (g == 1) ? (dInc + DINC_PER) : dInc;   // row paths
    const float* dB = (g == 0) ? dInc : (dInc + DINC_PER);   // col paths

    // per-lane dY cols j=2l, 2l+1 (VGPR pairs); lane63's yb clamped (benign)
    f2 ya[8], yb[8];
    {
        const int j0 = lane << 1;
        const int j1 = (j0 + 1 < 127) ? j0 + 1 : 126;
        const float4* A4 = (const float4*)(dB + b * 2032 + j0 * 16);
        const float4* B4 = (const float4*)(dB + b * 2032 + j1 * 16);
#pragma unroll
        for (int q = 0; q < 4; ++q) {
            float4 va = A4[q], vb = B4[q];
            ya[2*q]   = f2{va.x, va.y};  ya[2*q+1] = f2{va.z, va.w};
            yb[2*q]   = f2{vb.x, vb.y};  yb[2*q+1] = f2{vb.z, vb.w};
        }
    }

    // wave-uniform dX base -> s_load rows into SGPR pairs
    const int abase = __builtin_amdgcn_readfirstlane(a * 2032);
    const float4* Ar = (const float4*)(dA + abase);

    const f2 seed = f2{-0.25f, -0.25f};        // loop-invariant seed register

    f2 xA[8], xB[8];
    load_xrow(xA, Ar, 0);
    load_xrow(xB, Ar, 1);

    float g_lo = 1.0f, g_hi = 1.0f;
    float i0, i1;
    for (int r = 0; r < 126; r += 2) {
        row_dots(xA, ya, yb, seed, i0, i1);            // row r dots
        load_xrow(xA, Ar, (r + 2 < 127) ? r + 2 : 126); // prefetch
        recur(i0, i1, g_lo, g_hi);                     // row r scan
        row_dots(xB, ya, yb, seed, i0, i1);            // row r+1 dots
        load_xrow(xB, Ar, (r + 3 < 127) ? r + 3 : 126); // prefetch
        recur(i0, i1, g_lo, g_hi);                     // row r+1 scan
    }
    row_dots(xA, ya, yb, seed, i0, i1);                // row 126
    recur(i0, i1, g_lo, g_hi);

    const float kab = __builtin_bit_cast(float,
        __builtin_amdgcn_readlane(__builtin_bit_cast(int, g_lo), 63));
    if (lane == 0) red[wv] = weight * kab;
    __syncthreads();
    if (threadIdx.x == 0)
        atomicAdd(outp, (red[0] + red[1]) + (red[2] + red[3]));
}

// ---- fallback (ws too small): self-contained, raw inputs, q-trick ----
__global__ __launch_bounds__(256) void sig_pde_raw(
    const float* __restrict__ X, const float* __restrict__ Y,
    float* __restrict__ outp)
{
    __shared__ float red[4];
    const int wv = threadIdx.x >> 6, lane = threadIdx.x & 63;
    const int B = blockIdx.x;
    int g, a, b;
    if (B < XY_BLOCKS) { g = 2; a = B >> 4; b = ((B & 15) << 2) + wv; }
    else {
        int t = B - XY_BLOCKS; g = 0;
        if (t >= TRI_BLOCKS) { t -= TRI_BLOCKS; g = 1; }
        int aa = 0;
        for (;;) { int nb = (67 - aa) >> 2; if (t < nb) break; t -= nb; ++aa; }
        a = aa; b = aa + (t << 2) + wv;
    }
    float weight = (g == 2) ? (-2.0f / 4096.0f)
                            : ((a == b ? 1.0f : 2.0f) / 4096.0f);
    if (g < 2 && b > 63) { b = 63; weight = 0.0f; }
    const float* P = (g == 1) ? Y : X;
    const float* Q = (g == 0) ? X : Y;
    f2 ya[8], yb[8];
    {
        const float* Qb = Q + b * 2048;
        const int j0 = lane << 1;
        const int j2 = (j0 + 2 <= 127) ? j0 + 2 : 127;
        const float4* A4 = (const float4*)(Qb + j0 * 16);
        const float4* B4 = (const float4*)(Qb + (j0 + 1) * 16);
        const float4* C4 = (const float4*)(Qb + j2 * 16);
#pragma unroll
        for (int q = 0; q < 4; ++q) {
            float4 ra = A4[q], rb = B4[q], rc = C4[q];
            ya[2*q]   = f2{rb.x - ra.x, rb.y - ra.y};
            ya[2*q+1] = f2{rb.z - ra.z, rb.w - ra.w};
            yb[2*q]   = f2{rc.x - rb.x, rc.y - rb.y};
            yb[2*q+1] = f2{rc.z - rb.z, rc.w - rb.w};
        }
    }
    const int abase = __builtin_amdgcn_readfirstlane(a * 2048);
    const float4* Ar = (const float4*)(P + abase);
    const f2 seed = f2{-0.25f, -0.25f};
    f2 xA[8];
    float qpA, qpB, g_lo = 1.0f, g_hi = 1.0f;
    {
        load_xrow(xA, Ar, 0);
        float h0, h1;
        row_dots(xA, ya, yb, seed, h0, h1);    // dot(x_0,y) - 1
        qpA = h0 + 1.0f; qpB = h1 + 1.0f;      // dot(x_0,y)
    }
    for (int r = 0; r < 127; ++r) {
        load_xrow(xA, Ar, r + 1);
        float h0, h1;
        row_dots(xA, ya, yb, seed, h0, h1);    // dot(x_{r+1},y) - 1
        const float i0 = h0 - qpA;             // = inc - 1
        const float i1 = h1 - qpB;
        qpA = h0 + 1.0f; qpB = h1 + 1.0f;
        recur(i0, i1, g_lo, g_hi);
    }
    const float kab = __builtin_bit_cast(float,
        __builtin_amdgcn_readlane(__builtin_bit_cast(int, g_lo), 63));
    if (lane == 0) red[wv] = weight * kab;
    __syncthreads();
    if (threadIdx.x == 0)
        atomicAdd(outp, (red[0] + red[1]) + (red[2] + red[3]));
}

extern "C" void kernel_launch(void* const* d_in, const int* in_sizes, int n_in,
                              void* d_out, int out_size, void* d_ws, size_t ws_size,
                              hipStream_t stream) {
    const float* X = (const float*)d_in[0];
    const float* Y = (const float*)d_in[1];
    float* out = (float*)d_out;
    float* ws  = (float*)d_ws;

    hipMemsetAsync(d_out, 0, sizeof(float), stream);   // capturable memset node
    if (ws_size >= (size_t)(2 * DINC_PER) * sizeof(float)) {
        sig_diff<<<254, 256, 0, stream>>>(X, Y, ws);
        sig_pde7<<<NBLOCKS, 256, 0, stream>>>(ws, out);
    } else {
        sig_pde_raw<<<NBLOCKS, 256, 0, stream>>>(X, Y, out);
    }
}